// Round 4
// baseline (509.267 us; speedup 1.0000x reference)
//
#include <hip/hip_runtime.h>
#include <hip/hip_bf16.h>
#include <stdint.h>

// Bilinear: out[b,i,j,k] = sum_{p,q} x1[b,i,p] W[k,p,q] x2[b,j,q] + bias[k]
// B=8, L=256, P=Q=512, K=64.  Buffers are FP32 (values bf16-rounded upstream).
//
// Two NT GEMMs, fp32->bf16 conversion FUSED into LDS staging (no pre-convert
// buffers; workspace is only ~8 MiB):
//  Stage A: S[(b,j),(k,p)] = sum_q X2[(b,j),q] * W[(k,p),q]   (S bf16, in ws,
//           chunked 128 rows = 8 MiB at a time)
//  Stage B: out[b,i,(j,k)] = sum_p X1_b[i,p] * S_b[(j,k),p] + bias[k] (fp32)

typedef __bf16 bf16x8 __attribute__((ext_vector_type(8)));
typedef float  f32x4  __attribute__((ext_vector_type(4)));

#define BM 128
#define BN 128
#define BK 64
#define KDIM 512

__device__ inline bf16x8 load8_as_bf16(const float* p) {
    f32x4 a = *(const f32x4*)p;
    f32x4 b = *(const f32x4*)(p + 4);
    bf16x8 o;
    o[0]=(__bf16)a[0]; o[1]=(__bf16)a[1]; o[2]=(__bf16)a[2]; o[3]=(__bf16)a[3];
    o[4]=(__bf16)b[0]; o[5]=(__bf16)b[1]; o[6]=(__bf16)b[2]; o[7]=(__bf16)b[3];
    return o;
}
__device__ inline bf16x8 load8_as_bf16(const __bf16* p) {
    return *(const bf16x8*)p;
}

template <typename InA, typename InB, typename OutT>
__global__ __launch_bounds__(256) void gemm_nt(
    const InA* __restrict__ A,       // [M x 512] row-major
    const InB* __restrict__ B,       // [N x 512] row-major  (C = A * B^T)
    OutT* __restrict__ C,            // [M x ldc] row-major
    const float* __restrict__ bias,  // nullptr, or [64]: adds bias[col & 63]
    int ldc)
{
    const int tid  = threadIdx.x;
    const int lane = tid & 63;
    const int wave = tid >> 6;
    const int wm = wave & 1;
    const int wn = wave >> 1;

    const int m0 = blockIdx.y * BM;
    const int n0 = blockIdx.x * BN;

    __shared__ __bf16 sAt[BM * BK];  // [128 rows][64 k] row-major, 16 KiB
    __shared__ __bf16 sBt[BN * BK];

    f32x4 acc[4][4] = {};

    const int krow = lane >> 4;   // 0..3
    const int lcol = lane & 15;

    for (int kt = 0; kt < KDIM / BK; ++kt) {
        const InA* gA = A + (long)m0 * KDIM + kt * BK;
        const InB* gB = B + (long)n0 * KDIM + kt * BK;
        // Stage 16 KiB bf16 per tile: f = it*256+tid, row = f>>3, kchunk = f&7.
        // Load 8 elems (fp32: 32B, bf16: 16B), convert, ds_write_b128.
#pragma unroll
        for (int it = 0; it < 4; ++it) {
            int f = it * 256 + tid;
            int row = f >> 3, kc = f & 7;
            *(bf16x8*)&sAt[f * 8] = load8_as_bf16(gA + (long)row * KDIM + kc * 8);
        }
#pragma unroll
        for (int it = 0; it < 4; ++it) {
            int f = it * 256 + tid;
            int row = f >> 3, kc = f & 7;
            *(bf16x8*)&sBt[f * 8] = load8_as_bf16(gB + (long)row * KDIM + kc * 8);
        }
        __syncthreads();
#pragma unroll
        for (int kk = 0; kk < BK / 32; ++kk) {
            bf16x8 af[4], bfr[4];
#pragma unroll
            for (int i = 0; i < 4; ++i)
                af[i] = *(const bf16x8*)&sAt[(wm * 64 + i * 16 + lcol) * BK + kk * 32 + krow * 8];
#pragma unroll
            for (int j = 0; j < 4; ++j)
                bfr[j] = *(const bf16x8*)&sBt[(wn * 64 + j * 16 + lcol) * BK + kk * 32 + krow * 8];
#pragma unroll
            for (int i = 0; i < 4; ++i)
#pragma unroll
                for (int j = 0; j < 4; ++j)
                    acc[i][j] = __builtin_amdgcn_mfma_f32_16x16x32_bf16(af[i], bfr[j], acc[i][j], 0, 0, 0);
        }
        __syncthreads();
    }

    // Epilogue. C/D layout (16x16): col = lane&15, row = (lane>>4)*4 + reg.
#pragma unroll
    for (int j = 0; j < 4; ++j) {
        const int col = n0 + wn * 64 + j * 16 + lcol;
        float badd = bias ? bias[col & 63] : 0.f;
#pragma unroll
        for (int i = 0; i < 4; ++i) {
            const int rowb = m0 + wm * 64 + i * 16 + krow * 4;
#pragma unroll
            for (int r = 0; r < 4; ++r) {
                float v = acc[i][j][r] + badd;
                C[(long)(rowb + r) * ldc + col] = (OutT)v;
            }
        }
    }
}

extern "C" void kernel_launch(void* const* d_in, const int* in_sizes, int n_in,
                              void* d_out, int out_size, void* d_ws, size_t ws_size,
                              hipStream_t stream)
{
    (void)in_sizes; (void)n_in; (void)out_size;
    const float* x1 = (const float*)d_in[0];   // [8,256,512]  == [2048 x 512] rm
    const float* x2 = (const float*)d_in[1];   // [8,256,512]  == [2048 x 512] rm
    const float* W  = (const float*)d_in[2];   // [64,512,512] == [32768 x 512] rm
    const float* bs = (const float*)d_in[3];   // [64]
    float* out = (float*)d_out;                // [8,256,256,64] == per-b [256 x 16384]
    __bf16* S  = (__bf16*)d_ws;                // chunked [rows x 32768] bf16

    const long ROWS_TOTAL = 2048;              // S rows = (b,j) pairs
    const long ROW_ELEMS  = 32768;             // (k,p) per S row
    const size_t row_bytes = (size_t)ROW_ELEMS * sizeof(__bf16);  // 64 KiB

    long rows_chunk = (long)(ws_size / row_bytes);
    rows_chunk &= ~127L;                       // multiple of 128 (BM granularity)
    if (rows_chunk < 128) rows_chunk = 128;    // 8 MiB floor (R2-proven safe)
    if (rows_chunk > ROWS_TOTAL) rows_chunk = ROWS_TOTAL;

    for (long r0 = 0; r0 < ROWS_TOTAL; r0 += rows_chunk) {
        long rows = ROWS_TOTAL - r0;
        if (rows > rows_chunk) rows = rows_chunk;

        // Stage A: S[0..rows) = X2[r0..) @ W^T.  N = 32768, K = 512, bf16 out.
        dim3 gA(32768 / BN, (unsigned)(rows / BM), 1);
        gemm_nt<float, float, __bf16><<<gA, 256, 0, stream>>>(
            x2 + r0 * KDIM, W, S, nullptr, 32768);

        // Stage B: consume chunk -> fp32 out (+bias), per-b segments
        // (each segment a multiple of 128 S-rows inside one b).
        long seg = r0;
        while (seg < r0 + rows) {
            long b    = seg >> 8;
            long bend = (b + 1) << 8;
            long send = r0 + rows < bend ? r0 + rows : bend;
            long len  = send - seg;            // 128 or 256
            long j0   = seg & 255;
            dim3 gB((unsigned)((len * 64) / BN), 256 / BM, 1);
            gemm_nt<float, __bf16, float><<<gB, 256, 0, stream>>>(
                x1 + b * 256 * KDIM,
                S + (seg - r0) * ROW_ELEMS,    // segment as [(len*64) x 512]
                out + b * 256L * 16384 + j0 * 64,
                bs, 16384);
            seg = send;
        }
    }
}

// Round 6
// 344.687 us; speedup vs baseline: 1.4775x; 1.4775x over previous
//
#include <hip/hip_runtime.h>
#include <hip/hip_bf16.h>
#include <stdint.h>

// Bilinear: out[b,i,j,k] = sum_{p,q} x1[b,i,p] W[k,p,q] x2[b,j,q] + bias[k]
// B=8, L=256, P=Q=512, K=64.  Buffers fp32 (values bf16-rounded upstream).
//
// Structure (all pieces individually harness-proven):
//  - pre-convert W/x1/x2 -> bf16 into ws head (36 MiB)         [R5 first-pass]
//  - two NT GEMMs, explicit ds_write_b128 staging (NO global_load_lds —
//    that builtin diverged under graph replay in R5)            [R4 full-pass]
//  - LDS rows padded to 72 elems (144 B) to break the 16-way ds_read_b128
//    bank aliasing seen in R4 (SQ_LDS_BANK_CONFLICT 2.5e7/dispatch)
//  Stage A: S[(b,j),(k,p)] = sum_q X2b[(b,j),q] * Wb[(k,p),q]  (S bf16 in ws)
//  Stage B: out[b,i,(j,k)] = sum_p X1b[i,p] * S_b[(j,k),p] + bias[k] (fp32)

typedef __bf16 bf16x8 __attribute__((ext_vector_type(8)));
typedef float  f32x4  __attribute__((ext_vector_type(4)));

#define BM 128
#define BN 128
#define BK 64
#define LDSK 72   // padded LDS row stride (elems): 144 B -> bank rotation 4/row
#define KDIM 512

__global__ __launch_bounds__(256) void f32_to_bf16_kernel(
    const float* __restrict__ in, __bf16* __restrict__ out, long n8)
{
    for (long i = blockIdx.x * 256L + threadIdx.x; i < n8; i += gridDim.x * 256L) {
        f32x4 a = *(const f32x4*)(in + i * 8);
        f32x4 b = *(const f32x4*)(in + i * 8 + 4);
        bf16x8 o;
        o[0]=(__bf16)a[0]; o[1]=(__bf16)a[1]; o[2]=(__bf16)a[2]; o[3]=(__bf16)a[3];
        o[4]=(__bf16)b[0]; o[5]=(__bf16)b[1]; o[6]=(__bf16)b[2]; o[7]=(__bf16)b[3];
        *(bf16x8*)(out + i * 8) = o;
    }
}

template <typename OutT>
__global__ __launch_bounds__(256) void gemm_nt_bf16(
    const __bf16* __restrict__ A,    // [M x 512] row-major
    const __bf16* __restrict__ B,    // [N x 512] row-major  (C = A * B^T)
    OutT* __restrict__ C,            // [M x ldc] row-major
    const float* __restrict__ bias,  // nullptr, or [64]: adds bias[col & 63]
    int ldc,
    long sA, long sB, long sC)       // per-blockIdx.z strides (elements)
{
    const int tid  = threadIdx.x;
    const int lane = tid & 63;
    const int wave = tid >> 6;
    const int wm = wave & 1;
    const int wn = wave >> 1;
    const long z = blockIdx.z;
    A += z * sA;  B += z * sB;  C += z * sC;

    const int m0 = blockIdx.y * BM;
    const int n0 = blockIdx.x * BN;

    __shared__ __bf16 sAt[BM * LDSK];  // [128 rows][72], 18 KiB each
    __shared__ __bf16 sBt[BN * LDSK];

    f32x4 acc[4][4] = {};

    const int krow = lane >> 4;   // 0..3
    const int lcol = lane & 15;

    // Staging indices: f = it*256+tid in [0,1024); row = f>>3, kchunk = f&7.
    const int srow = tid >> 3;    // per-it row base offset handled via +32*it
    const int skc  = tid & 7;

    for (int kt = 0; kt < KDIM / BK; ++kt) {
        const __bf16* gA = A + (long)m0 * KDIM + kt * BK;
        const __bf16* gB = B + (long)n0 * KDIM + kt * BK;
#pragma unroll
        for (int it = 0; it < 4; ++it) {
            int row = it * 32 + srow;
            *(bf16x8*)&sAt[row * LDSK + skc * 8] =
                *(const bf16x8*)(gA + (long)row * KDIM + skc * 8);
        }
#pragma unroll
        for (int it = 0; it < 4; ++it) {
            int row = it * 32 + srow;
            *(bf16x8*)&sBt[row * LDSK + skc * 8] =
                *(const bf16x8*)(gB + (long)row * KDIM + skc * 8);
        }
        __syncthreads();
#pragma unroll
        for (int kk = 0; kk < BK / 32; ++kk) {
            bf16x8 af[4], bfr[4];
#pragma unroll
            for (int i = 0; i < 4; ++i)
                af[i] = *(const bf16x8*)&sAt[(wm * 64 + i * 16 + lcol) * LDSK + kk * 32 + krow * 8];
#pragma unroll
            for (int j = 0; j < 4; ++j)
                bfr[j] = *(const bf16x8*)&sBt[(wn * 64 + j * 16 + lcol) * LDSK + kk * 32 + krow * 8];
#pragma unroll
            for (int i = 0; i < 4; ++i)
#pragma unroll
                for (int j = 0; j < 4; ++j)
                    acc[i][j] = __builtin_amdgcn_mfma_f32_16x16x32_bf16(af[i], bfr[j], acc[i][j], 0, 0, 0);
        }
        __syncthreads();
    }

    // Epilogue. C/D layout (16x16): col = lane&15, row = (lane>>4)*4 + reg.
#pragma unroll
    for (int j = 0; j < 4; ++j) {
        const int col = n0 + wn * 64 + j * 16 + lcol;
        float badd = bias ? bias[col & 63] : 0.f;
#pragma unroll
        for (int i = 0; i < 4; ++i) {
            const int rowb = m0 + wm * 64 + i * 16 + krow * 4;
#pragma unroll
            for (int r = 0; r < 4; ++r) {
                float v = acc[i][j][r] + badd;
                C[(long)(rowb + r) * ldc + col] = (OutT)v;
            }
        }
    }
}

extern "C" void kernel_launch(void* const* d_in, const int* in_sizes, int n_in,
                              void* d_out, int out_size, void* d_ws, size_t ws_size,
                              hipStream_t stream)
{
    (void)in_sizes; (void)n_in; (void)out_size;
    const float* x1f = (const float*)d_in[0];  // [8,256,512]  == [2048 x 512] rm
    const float* x2f = (const float*)d_in[1];  // [8,256,512]
    const float* Wf  = (const float*)d_in[2];  // [64,512,512] == [32768 x 512] rm
    const float* bs  = (const float*)d_in[3];  // [64] fp32
    float* out = (float*)d_out;                // [8,256,256,64] == per-b [256 x 16384]

    // ws layout (bf16): [Wb 32MiB][x1b 2MiB][x2b 2MiB][S chunk ...]
    const long N_W = 64L * 512 * 512;          // 16,777,216 elems
    const long N_X = 8L * 256 * 512;           // 1,048,576 elems
    __bf16* Wb  = (__bf16*)d_ws;
    __bf16* x1b = Wb + N_W;
    __bf16* x2b = x1b + N_X;
    __bf16* S   = x2b + N_X;
    const size_t head_bytes = (size_t)(N_W + 2 * N_X) * sizeof(__bf16); // 36 MiB

    f32_to_bf16_kernel<<<2048, 256, 0, stream>>>(Wf,  Wb,  N_W / 8);
    f32_to_bf16_kernel<<<512,  256, 0, stream>>>(x1f, x1b, N_X / 8);
    f32_to_bf16_kernel<<<512,  256, 0, stream>>>(x2f, x2b, N_X / 8);

    const long ROWS_TOTAL = 2048;              // S rows = (b,j) pairs
    const long ROW_ELEMS  = 32768;             // (k,p) per S row (64 KiB bf16)

    // Chunk = whole b's (multiple of 256 rows) fitting ws after the head.
    long rows_chunk = (ws_size > head_bytes)
        ? (long)((ws_size - head_bytes) / (ROW_ELEMS * sizeof(__bf16))) : 0;
    rows_chunk &= ~255L;
    if (rows_chunk < 256) rows_chunk = 256;    // ws >= 128 MiB (R4-proven)
    if (rows_chunk > ROWS_TOTAL) rows_chunk = ROWS_TOTAL;

    for (long r0 = 0; r0 < ROWS_TOTAL; r0 += rows_chunk) {
        long rows = ROWS_TOTAL - r0;
        if (rows > rows_chunk) rows = rows_chunk;
        long nbc = rows >> 8;                  // whole batches this chunk

        // Stage A: S[0..rows) = X2b[r0..) @ Wb^T.  N = 32768, K = 512, bf16.
        dim3 gA(32768 / BN, (unsigned)(rows / BM), 1);
        gemm_nt_bf16<__bf16><<<gA, 256, 0, stream>>>(
            x2b + r0 * KDIM, Wb, S, nullptr, 32768, 0, 0, 0);

        // Stage B: z-batched over the chunk's b's -> fp32 out (+bias).
        dim3 gB(16384 / BN, 256 / BM, (unsigned)nbc);
        gemm_nt_bf16<float><<<gB, 256, 0, stream>>>(
            x1b + r0 * KDIM,                   // X1_b rows
            S,                                 // S_b as [16384 x 512]
            out + r0 * 16384,                  // out_b as [256 x 16384]
            bs, 16384,
            256L * KDIM,                       // sA: next b in X1
            256L * ROW_ELEMS,                  // sB: next b in S
            256L * 16384);                     // sC: next b in out
    }
}